// Round 2
// baseline (108.907 us; speedup 1.0000x reference)
//
#include <hip/hip_runtime.h>
#include <stdint.h>

// SpottingLoss: B=2048 batches, N=64, F=19. Two-phase greedy bipartite
// matching (ref: lax.scan x64 x2) + permuted loss -> single scalar.
//
// One block == one wave == one batch; lane i owns row i.
// Exactness (validated absmax 0.0 in R1):
//  - alpha,v,h are exactly {0,1}; D2 == D1 masked by active-column bitmask.
//  - Row argmax: strict '>' scan == first-index tie-break.
//  - Column argmax via packed key max: (tag<<38)|(val_bits<<6)|(63-row).
//    val in (0,1] -> positive-float bits monotone; larger (63-row) == smaller
//    row == JAX first-index tie-break. tag identifies "written this round",
//    replacing the per-round baseline re-init (stale keys have older tags).
//  - Any column receiving >=1 positive bid this round is matched to its best
//    bidder (C picks that row, A already set) -> colkill == "fresh tag".
//  - Early exit when no live rows: remaining scan steps are provably no-ops.
//
// Single-wave blocks: a wave's DS instructions execute in program order, so
// ds_max -> ds_read ordering needs no s_barrier. wave_barrier() pins compiler
// scheduling at zero runtime cost. (R1 had 3 __syncthreads per round; each
// forces a full waitcnt drain -- the dominant stall at 2 waves/SIMD.)

#define NN 64
#define NF 19
#define ROWF (NN * NF)    // 1216 floats per batch per tensor
#define ROW4 (ROWF / 4)   // 304 float4

__global__ __launch_bounds__(64) void spotting_loss_kernel(
    const float* __restrict__ yt, const float* __restrict__ yp,
    float* __restrict__ out)
{
  const int b = blockIdx.x;
  const int i = threadIdx.x;  // row index == lane

  __shared__ float yt_sh[ROWF];
  __shared__ float yp_sh[ROWF];
  __shared__ float p_sh[NN];
  __shared__ unsigned long long key_sh[NN];

  // ---- coalesced float4 staging of both batch slabs (4864 B each) ----
  const float4* __restrict__ yt4 = (const float4*)(yt + (size_t)b * ROWF);
  const float4* __restrict__ yp4 = (const float4*)(yp + (size_t)b * ROWF);
  float4* yt_sh4 = (float4*)yt_sh;
  float4* yp_sh4 = (float4*)yp_sh;
#pragma unroll
  for (int t = 0; t < 5; ++t) {
    const int idx = t * NN + i;
    if (idx < ROW4) {
      yt_sh4[idx] = yt4[idx];
      yp_sh4[idx] = yp4[idx];
    }
  }
  key_sh[i] = 0ull;  // tag 0 == "never written"
  __syncthreads();   // once; single wave -> cheap

  const float alpha = yt_sh[i * NF + 0];
  const float x     = yt_sh[i * NF + 1];
  p_sh[i] = yp_sh[i * NF + 1];   // compact p for vectorized broadcast reads
  __syncthreads();               // once more; then barrier-free

  // ---- D1 row in registers via float4 broadcast reads ----
  float D1r[NN];
  const float4* __restrict__ p4 = (const float4*)p_sh;
#pragma unroll
  for (int j4 = 0; j4 < NN / 4; ++j4) {
    const float4 pv = p4[j4];
    D1r[4 * j4 + 0] = 1.0f - fabsf(x - pv.x);
    D1r[4 * j4 + 1] = 1.0f - fabsf(x - pv.y);
    D1r[4 * j4 + 2] = 1.0f - fabsf(x - pv.z);
    D1r[4 * j4 + 3] = 1.0f - fabsf(x - pv.w);
  }

  unsigned long long hbits = ~0ull;  // active columns
  int perm = 0, jmax = 0;
  float best = 0.0f;
  unsigned tag = 0;

  for (int phase = 0; phase < 2; ++phase) {
    bool vlive  = (phase == 0) ? (alpha > 0.5f) : (alpha < 0.5f);
    bool rescan = vlive;

    for (int it = 0; it < NN; ++it) {
      if (__ballot(vlive) == 0ull) break;
      ++tag;

      if (rescan) {  // first-index argmax over active-column-masked D1
        const unsigned hlo = (unsigned)hbits;
        const unsigned hhi = (unsigned)(hbits >> 32);
        best = -1.0f; jmax = 0;
#pragma unroll
        for (int j = 0; j < NN; ++j) {
          const unsigned bit = (j < 32) ? ((hlo >> j) & 1u)
                                        : ((hhi >> (j - 32)) & 1u);
          const float t = __uint_as_float(__float_as_uint(D1r[j]) & (0u - bit));
          if (t > best) { best = t; jmax = j; }
        }
        rescan = false;
      }

      if (vlive && best > 0.0f) {
        const unsigned long long key =
            ((unsigned long long)tag << 38) |
            ((unsigned long long)__float_as_uint(best) << 6) |
            (unsigned long long)(63 - i);
        atomicMax(&key_sh[jmax], key);
      }
      __builtin_amdgcn_wave_barrier();  // pin: reads below stay after atomic

      const unsigned long long kc = key_sh[i];  // lane i == column i
      const unsigned long long killed =
          __ballot((unsigned)(kc >> 38) == tag);

      if (vlive && best > 0.0f) {
        const unsigned long long kw = key_sh[jmax];
        if ((int)(63ull - (kw & 63ull)) == i) {  // mutual match
          perm = jmax;
          vlive = false;
        } else if ((killed >> jmax) & 1ull) {
          rescan = true;  // favorite column taken by a stronger bidder
        }
      }
      hbits &= ~killed;
      __builtin_amdgcn_wave_barrier();
    }
  }

  // ---- loss (all operands from LDS) ----
  const float a = alpha;
  const int pbase = perm * NF;
  const float p0 = yp_sh[pbase + 0];
  const float p1 = yp_sh[pbase + 1];
  const float dx = x - p1;
  const float da = a - p0;
  float s2 = 0.0f;
#pragma unroll
  for (int f = 2; f < NF; ++f) {
    const float d = yt_sh[i * NF + f] - yp_sh[pbase + f];
    s2 += d * d;
  }
  float l = a * 5.0f * (dx * dx)
          + a * (da * da)
          + (1.0f - a) * 0.5f * (da * da)
          + a * s2;

#pragma unroll
  for (int off = 32; off > 0; off >>= 1) l += __shfl_down(l, off);
  if (i == 0) atomicAdd(out, l);
}

extern "C" void kernel_launch(void* const* d_in, const int* in_sizes, int n_in,
                              void* d_out, int out_size, void* d_ws, size_t ws_size,
                              hipStream_t stream) {
  const float* yt = (const float*)d_in[0];
  const float* yp = (const float*)d_in[1];
  float* out = (float*)d_out;
  const int B = in_sizes[0] / ROWF;

  hipMemsetAsync(out, 0, sizeof(float) * (size_t)out_size, stream);
  spotting_loss_kernel<<<B, 64, 0, stream>>>(yt, yp, out);
}